// Round 6
// baseline (230.470 us; speedup 1.0000x reference)
//
#include <hip/hip_runtime.h>

#define NXD 128
#define NYD 128
#define SRC_XD 64
#define SRC_YD 64
#define T_STEPSD 256
#define BATCHD 8
#define N_PROBESD 4

typedef float v2f __attribute__((ext_vector_type(2)));

// DPP cross-lane single shifts across the full wave64.
// WAVE_SHR1 (0x138): lane i <- lane i-1, lane0 -> 0 (bound_ctrl)
// WAVE_SHL1 (0x130): lane i <- lane i+1, lane63 -> 0
// Zero-fill matches the conv 'SAME' zero padding at col -1 / col 128.
__device__ __forceinline__ float dpp_from_lower(float v) {
    return __int_as_float(__builtin_amdgcn_update_dpp(0, __float_as_int(v), 0x138, 0xF, 0xF, true));
}
__device__ __forceinline__ float dpp_from_upper(float v) {
    return __int_as_float(__builtin_amdgcn_update_dpp(0, __float_as_int(v), 0x130, 0xF, 0xF, true));
}

// One row update (2 cells): lap = up + dn + {lf+Y.y, Y.x+rt} - 4Y;
// Z = K*lap + (C2 + K2*Z)   (Z holds prev field, overwritten in place)
#define ROW(up, dn, Yr, Zr, Kr) { \
    const float lf = dpp_from_lower((Yr).y); \
    const float rt = dpp_from_upper((Yr).x); \
    v2f cross; cross.x = lf + (Yr).y; cross.y = (Yr).x + rt; \
    const v2f lap = (up) + (dn) + cross - 4.0f * (Yr); \
    (Zr) = (Kr) * lap + (C2v + K2v * (Zr)); \
}

// Wave-uniform 16-way register select (ro is an SGPR -> scalar branch tree).
#define PSEL(ro, Z, pv) switch (ro) { \
    case 0:  pv = (Z##0);  break; \
    case 1:  pv = (Z##1);  break; \
    case 2:  pv = (Z##2);  break; \
    case 3:  pv = (Z##3);  break; \
    case 4:  pv = (Z##4);  break; \
    case 5:  pv = (Z##5);  break; \
    case 6:  pv = (Z##6);  break; \
    case 7:  pv = (Z##7);  break; \
    case 8:  pv = (Z##8);  break; \
    case 9:  pv = (Z##9);  break; \
    case 10: pv = (Z##10); break; \
    case 11: pv = (Z##11); break; \
    case 12: pv = (Z##12); break; \
    case 13: pv = (Z##13); break; \
    case 14: pv = (Z##14); break; \
    default: pv = (Z##15); break; \
}

#define PROBES(Z) \
    if (whas0) { v2f pv; PSEL(pro0s, Z, pv) accv0 += pv * pv; } \
    if (whas1) { v2f pv; PSEL(pro1s, Z, pv) accv1 += pv * pv; } \
    if (whas2) { v2f pv; PSEL(pro2s, Z, pv) accv2 += pv * pv; } \
    if (whas3) { v2f pv; PSEL(pro3s, Z, pv) accv3 += pv * pv; }

// Fused 2-step iteration, ONE barrier per 2 steps.
// Entry: a* = y^t (band rows 16w..16w+15), b* = y^{t-1}.
// LDS buffer p = (t/2)&1 holds neighbor rows: cur (y^t) R0,R1,R14,R15 and
// prev (y^{t-1}) R0,R15 per wave; slot 8 = permanent zero ghost.
// Exit: a* = y^{t+2}, b* = y^{t+1}; published into buffer p^1.
#define FSTEP(tt) { \
    const int p_ = ((tt) >> 1) & 1, np_ = p_ ^ 1; \
    const v2f u1 = *(const v2f*)&cB15[p_][wa][colb];   /* y^t[R0-1]   */ \
    const v2f u2 = *(const v2f*)&cB14[p_][wa][colb];   /* y^t[R0-2]   */ \
    v2f pu1      = *(const v2f*)&pB15[p_][wa][colb];   /* y^{t-1}[R0-1]*/ \
    const v2f d1 = *(const v2f*)&cT0[p_][wb][colb];    /* y^t[R15+1]  */ \
    const v2f d2 = *(const v2f*)&cT1[p_][wb][colb];    /* y^t[R15+2]  */ \
    v2f pd1      = *(const v2f*)&pT0[p_][wb][colb];    /* y^{t-1}[R15+1]*/ \
    const float xt0 = xs[tt], xt1 = xs[(tt) + 1]; \
    /* extended rows at t+1 (in place over pu1/pd1) */ \
    ROW(u2,  a0, u1, pu1, ku) \
    ROW(a15, d2, d1, pd1, kd) \
    if (w == 3) { if (l == (SRC_YD >> 1)) pd1.x += xt0; }  /* row 64 = wave3's R15+1 */ \
    if (w == 0) pu1 = zz;   /* ghost row -1 stays 0 (update has const term!) */ \
    if (w == 7) pd1 = zz;   /* ghost row 128 */ \
    /* step A: y^{t+1} into b* */ \
    ROW(u1,   a1,  a0,  b0,  k0) \
    ROW(a0,   a2,  a1,  b1,  k1) \
    ROW(a1,   a3,  a2,  b2,  k2) \
    ROW(a2,   a4,  a3,  b3,  k3) \
    ROW(a3,   a5,  a4,  b4,  k4) \
    ROW(a4,   a6,  a5,  b5,  k5) \
    ROW(a5,   a7,  a6,  b6,  k6) \
    ROW(a6,   a8,  a7,  b7,  k7) \
    ROW(a7,   a9,  a8,  b8,  k8) \
    ROW(a8,   a10, a9,  b9,  k9) \
    ROW(a9,   a11, a10, b10, k10) \
    ROW(a10,  a12, a11, b11, k11) \
    ROW(a11,  a13, a12, b12, k12) \
    ROW(a12,  a14, a13, b13, k13) \
    ROW(a13,  a15, a14, b14, k14) \
    ROW(a14,  d1,  a15, b15, k15) \
    if (has_src) { if (own_src) b0.x += xt0; } \
    PROBES(b) \
    /* step B: y^{t+2} into a* */ \
    ROW(pu1,  b1,  b0,  a0,  k0) \
    ROW(b0,   b2,  b1,  a1,  k1) \
    ROW(b1,   b3,  b2,  a2,  k2) \
    ROW(b2,   b4,  b3,  a3,  k3) \
    ROW(b3,   b5,  b4,  a4,  k4) \
    ROW(b4,   b6,  b5,  a5,  k5) \
    ROW(b5,   b7,  b6,  a6,  k6) \
    ROW(b6,   b8,  b7,  a7,  k7) \
    ROW(b7,   b9,  b8,  a8,  k8) \
    ROW(b8,   b10, b9,  a9,  k9) \
    ROW(b9,   b11, b10, a10, k10) \
    ROW(b10,  b12, b11, a11, k11) \
    ROW(b11,  b13, b12, a12, k12) \
    ROW(b12,  b14, b13, a13, k13) \
    ROW(b13,  b15, b14, a14, k14) \
    ROW(b14,  pd1, b15, a15, k15) \
    if (has_src) { if (own_src) a0.x += xt1; } \
    PROBES(a) \
    /* publish new edges into the other buffer, then the ONLY barrier */ \
    *(v2f*)&cT0[np_][w][colb]  = a0; \
    *(v2f*)&cT1[np_][w][colb]  = a1; \
    *(v2f*)&cB14[np_][w][colb] = a14; \
    *(v2f*)&cB15[np_][w][colb] = a15; \
    *(v2f*)&pT0[np_][w][colb]  = b0; \
    *(v2f*)&pB15[np_][w][colb] = b15; \
    __syncthreads(); \
}

// 512 threads = 8 waves = 2/EU = 1 block/CU (grid is 8 blocks on 8 CUs).
// amdgpu_waves_per_eu(2,2): __launch_bounds__' 2nd arg is only a MIN --
// rounds 3/5 showed the allocator targeting higher occupancy and parking
// state in AGPRs (VGPR_Count 36/72 + accvgpr moves). The max=2 pins the
// unified budget at 256 regs/wave so the ~150-reg state stays in arch VGPRs.
__global__ __launch_bounds__(512)
__attribute__((amdgpu_waves_per_eu(2, 2)))
void wave_sim(
        const float* __restrict__ x,        // (T,B)
        const float* __restrict__ c,        // (NX,NY)
        const int*   __restrict__ probes,   // (4,2) int
        float* __restrict__ partial)        // (B,4)
{
    __shared__ float cT0[2][9][NYD];    // y^t   row R0   per wave; [8]=zero ghost
    __shared__ float cT1[2][9][NYD];    // y^t   row R1
    __shared__ float cB14[2][9][NYD];   // y^t   row R14
    __shared__ float cB15[2][9][NYD];   // y^t   row R15
    __shared__ float pT0[2][9][NYD];    // y^{t-1} row R0
    __shared__ float pB15[2][9][NYD];   // y^{t-1} row R15
    __shared__ float xs[T_STEPSD];

    const int tid = threadIdx.x;
    const int w = tid >> 6;       // wave 0..7, owns rows 16w..16w+15
    const int l = tid & 63;       // lane, owns cols 2l, 2l+1
    const int b = blockIdx.x;

    const float dt = 0.5f, bdamp = 0.005f;
    const float denom = 1.0f / (dt * dt) + 0.5f * bdamp / dt;  // 4.005
    const float inv_denom = 1.0f / denom;
    const float C2 = 2.0f * inv_denom;
    const float K2 = (-1.0f - dt * bdamp) * inv_denom;
    const float KL = dt * dt * inv_denom;
    v2f C2v; C2v.x = C2; C2v.y = C2;
    v2f K2v; K2v.x = K2; K2v.y = K2;
    v2f zz; zz.x = 0.0f; zz.y = 0.0f;

    // zero all halo buffers (y^0 = y^{-1} = 0; ghost slots stay 0 forever)
    for (int i = tid; i < 2 * 9 * NYD; i += 512) {
        ((float*)cT0)[i] = 0.0f;  ((float*)cT1)[i] = 0.0f;
        ((float*)cB14)[i] = 0.0f; ((float*)cB15)[i] = 0.0f;
        ((float*)pT0)[i] = 0.0f;  ((float*)pB15)[i] = 0.0f;
    }
    if (tid < T_STEPSD) xs[tid] = x[tid * BATCHD + b];

    const int rowbase = w * 16;
    const int colb = 2 * l;
#define LOADK(r) \
    v2f k##r; { \
        const v2f cc = *(const v2f*)&c[(rowbase + r) * NYD + colb]; \
        k##r = KL * cc * cc; \
    }
    LOADK(0) LOADK(1) LOADK(2) LOADK(3) LOADK(4) LOADK(5) LOADK(6) LOADK(7)
    LOADK(8) LOADK(9) LOADK(10) LOADK(11) LOADK(12) LOADK(13) LOADK(14) LOADK(15)
#undef LOADK
    // coefficients for the two extended halo rows (clamped; edge results are
    // forced to zero anyway, the clamp only avoids OOB)
    const int ru = (rowbase == 0) ? 0 : rowbase - 1;
    const int rd = (rowbase + 16 > 127) ? 127 : rowbase + 16;
    v2f ku, kd;
    { const v2f cc = *(const v2f*)&c[ru * NYD + colb]; ku = KL * cc * cc; }
    { const v2f cc = *(const v2f*)&c[rd * NYD + colb]; kd = KL * cc * cc; }

    v2f a0 = zz, a1 = zz, a2 = zz, a3 = zz, a4 = zz, a5 = zz, a6 = zz, a7 = zz,
        a8 = zz, a9 = zz, a10 = zz, a11 = zz, a12 = zz, a13 = zz, a14 = zz, a15 = zz;
    v2f b0 = zz, b1 = zz, b2 = zz, b3 = zz, b4 = zz, b5 = zz, b6 = zz, b7 = zz,
        b8 = zz, b9 = zz, b10 = zz, b11 = zz, b12 = zz, b13 = zz, b14 = zz, b15 = zz;

    // probes (wave-uniform coordinates)
    const int px0 = probes[0] & 127, py0 = probes[1] & 127;
    const int px1 = probes[2] & 127, py1 = probes[3] & 127;
    const int px2 = probes[4] & 127, py2 = probes[5] & 127;
    const int px3 = probes[6] & 127, py3 = probes[7] & 127;
    const bool own0 = ((px0 >> 4) == w) && ((py0 >> 1) == l);
    const bool own1 = ((px1 >> 4) == w) && ((py1 >> 1) == l);
    const bool own2 = ((px2 >> 4) == w) && ((py2 >> 1) == l);
    const bool own3 = ((px3 >> 4) == w) && ((py3 >> 1) == l);
    const bool whas0 = __ballot(own0) != 0ULL;
    const bool whas1 = __ballot(own1) != 0ULL;
    const bool whas2 = __ballot(own2) != 0ULL;
    const bool whas3 = __ballot(own3) != 0ULL;
    const int pro0s = __builtin_amdgcn_readfirstlane(px0 & 15);
    const int pro1s = __builtin_amdgcn_readfirstlane(px1 & 15);
    const int pro2s = __builtin_amdgcn_readfirstlane(px2 & 15);
    const int pro3s = __builtin_amdgcn_readfirstlane(px3 & 15);
    const int pel0 = py0 & 1, pel1 = py1 & 1, pel2 = py2 & 1, pel3 = py3 & 1;
    v2f accv0 = zz, accv1 = zz, accv2 = zz, accv3 = zz;

    const bool has_src = (w == (SRC_XD >> 4));            // wave 4 (row 64 = its R0)
    const bool own_src = has_src && (l == (SRC_YD >> 1)); // SRC_YD even -> .x

    const int wa = (w == 0) ? 8 : w - 1;    // 8 = zero ghost slot
    const int wb = (w == 7) ? 8 : w + 1;

    __syncthreads();

#pragma unroll 1
    for (int t = 0; t < T_STEPSD; t += 2) {
        FSTEP(t)
    }

    if (own0) partial[b * N_PROBESD + 0] = pel0 ? accv0.y : accv0.x;
    if (own1) partial[b * N_PROBESD + 1] = pel1 ? accv1.y : accv1.x;
    if (own2) partial[b * N_PROBESD + 2] = pel2 ? accv2.y : accv2.x;
    if (own3) partial[b * N_PROBESD + 3] = pel3 ? accv3.y : accv3.x;
}

__global__ void reduce_k(const float* __restrict__ partial, float* __restrict__ out) {
    const int p = threadIdx.x;
    if (p < N_PROBESD) {
        float s = 0.0f, tot = 0.0f;
        for (int bb = 0; bb < BATCHD; ++bb) s += partial[bb * N_PROBESD + p];
        for (int i = 0; i < BATCHD * N_PROBESD; ++i) tot += partial[i];
        out[p] = s / tot;
    }
}

extern "C" void kernel_launch(void* const* d_in, const int* in_sizes, int n_in,
                              void* d_out, int out_size, void* d_ws, size_t ws_size,
                              hipStream_t stream) {
    const float* x      = (const float*)d_in[0];
    const float* c      = (const float*)d_in[1];
    const int*   probes = (const int*)d_in[2];
    float* out = (float*)d_out;
    float* partial = (float*)d_ws;

    wave_sim<<<BATCHD, 512, 0, stream>>>(x, c, probes, partial);
    reduce_k<<<1, 64, 0, stream>>>(partial, out);
}